// Round 7
// baseline (461.447 us; speedup 1.0000x reference)
//
#include <hip/hip_runtime.h>
#include <cstdint>

// SpikingCNN: B=8192, D=784, H=128, O=10, T=20, beta=0.9, thr=1.0
// R23: fill the VALU idle. R22 counters: VALUBusy 88%, busy TIME ~288us ==
// R16/R17's busy time -> VALU-throughput-bound confirmed; residual = 12%
// idle (grid 512 = only 2 blocks/CU, occupancy 22.5%) + ~73us outside.
// Change: 8-row blocks, grid 1024 -> 4 blocks/CU (4 waves/SIMD, VGPR ~76 <=
// 128 ok, LDS 20.5KB x4 = 82KB ok). sM keeps 16 rows; rows 8..15 zeroed once
// so phase-2 16-row A-fragments read zeros; garbage LIF rows never stored
// (mask store lane<8). MFMA/CU doubles (13.5->27% util, headroom 4x); wp
// reads double (L2-resident). Phase-1 RNG, GEMM accumulation order, LIF
// math bit-identical to R22 (absmax 0.0).
// R22 history: fused spikegen+GEMM+LIF1, masks at ws offset 0 (aliasing fix),
// cur1 round-trip + lif1 kernel deleted. prep / lif2 byte-identical.

#define T_STEPS 20
#define B_SZ   8192
#define D_SZ   784
#define H_SZ   128
#define O_SZ   10
#define MASKS_OFF   0u                        // masks: 2,621,440 B (old cur1 area)
#define WP_OFF      84541440u                 // weight planes: 614,400 B
#define THR_OFF     101539840u                // thresholds: 8192*800*4 = 26,214,400 B

typedef __attribute__((ext_vector_type(8))) short short8;
typedef __attribute__((ext_vector_type(4))) float f32x4;
typedef unsigned short ushort_t;

// rotl via v_alignbit_b32 (r15-verified: 1 instr/round).
#define ROTL_ASM(dst, src, sh)                                        \
  asm("v_alignbit_b32 %0, %1, %1, %2" : "=v"(dst) : "v"(src), "n"(32 - (sh)))

// JAX threefry2x32, key = (0, 42), counter = (0, c1). Injection adds fused
// via v_add3_u32 (associative u32 adds: bit-exact; R19-verified).
__device__ __forceinline__ void threefry_0_42(uint32_t c1,
                                              uint32_t& o0, uint32_t& o1) {
  const uint32_t ks1 = 42u;
  const uint32_t ks2 = 42u ^ 0x1BD11BDAu;
  uint32_t x0, x1, r;
  x1 = c1 + ks1;                 // x0 = c0 + ks0 = 0
  x0 = x1;                       // round 1: x0 = 0 + x1
  ROTL_ASM(r, x1, 13); x1 = r ^ x0;
#define TF_R(rot) { x0 += x1; ROTL_ASM(r, x1, rot); x1 = r ^ x0; }
#define TF_IR(C1, K0, rot) { x1 += (C1); x0 = x0 + (K0) + x1; \
                             ROTL_ASM(r, x1, rot); x1 = r ^ x0; }
  TF_R(15) TF_R(26) TF_R(6)
  TF_IR(ks2 + 1u, ks1, 17) TF_R(29) TF_R(16) TF_R(24)
  TF_IR(2u,       ks2, 13) TF_R(15) TF_R(26) TF_R(6)
  TF_IR(ks1 + 3u, 0u,  17) TF_R(29) TF_R(16) TF_R(24)
  TF_IR(ks2 + 4u, ks1, 13) TF_R(15) TF_R(26) TF_R(6)
#undef TF_R
#undef TF_IR
  x0 += ks2; x1 += 5u;           // final injection (ks0+5 = 5)
  o0 = x0; o1 = x1;
}

__device__ __forceinline__ uint32_t rne_bf16_bits(float f) {
  uint32_t u = __float_as_uint(f);
  return (u + 0x7fffu + ((u >> 16) & 1u)) & 0xffff0000u;
}

// ---------------------------------------------------------------------------
// P: prep. Blocks 0..127: split w1 into 3 exact bf16 planes [128][800].
// Blocks 128..3327: pre-shifted thresholds thresh[b][d] = ceil(x*2^23)<<9,
// d in [784,800) padded 0 (never spikes; hits only zero weights).
// ---------------------------------------------------------------------------
__global__ __launch_bounds__(256) void prep(
    const float* __restrict__ w1, const float* __restrict__ x,
    ushort_t* __restrict__ wp, uint32_t* __restrict__ thresh) {
  if (blockIdx.x < 128) {
    const int h = blockIdx.x;
    for (int k = threadIdx.x; k < 800; k += 256) {
      float w = (k < D_SZ) ? w1[h * D_SZ + k] : 0.0f;
      uint32_t hb = rne_bf16_bits(w);
      float hi = __uint_as_float(hb);
      float r1 = w - hi;                      // exact
      uint32_t mb = rne_bf16_bits(r1);
      float mid = __uint_as_float(mb);
      float lo = r1 - mid;                    // exact
      uint32_t lb = __float_as_uint(lo);
      wp[0 * 102400 + h * 800 + k] = (ushort_t)(hb >> 16);
      wp[1 * 102400 + h * 800 + k] = (ushort_t)(mb >> 16);
      wp[2 * 102400 + h * 800 + k] = (ushort_t)(lb >> 16);
    }
  } else {
    const int gid = (blockIdx.x - 128) * 256 + threadIdx.x;  // 0..819199
    const int b = gid / 100;
    const int y = gid - b * 100;
    const int d0 = y << 3;
    uint4 T0 = {0u, 0u, 0u, 0u}, T1 = {0u, 0u, 0u, 0u};
    if (y < 98) {                                  // d0+7 <= 783
      const float* xr = x + (size_t)b * D_SZ + d0;
      float4 v0 = *(const float4*)xr;
      float4 v1 = *(const float4*)(xr + 4);
      T0.x = (uint32_t)__builtin_ceilf(v0.x * 8388608.0f) << 9;
      T0.y = (uint32_t)__builtin_ceilf(v0.y * 8388608.0f) << 9;
      T0.z = (uint32_t)__builtin_ceilf(v0.z * 8388608.0f) << 9;
      T0.w = (uint32_t)__builtin_ceilf(v0.w * 8388608.0f) << 9;
      T1.x = (uint32_t)__builtin_ceilf(v1.x * 8388608.0f) << 9;
      T1.y = (uint32_t)__builtin_ceilf(v1.y * 8388608.0f) << 9;
      T1.z = (uint32_t)__builtin_ceilf(v1.z * 8388608.0f) << 9;
      T1.w = (uint32_t)__builtin_ceilf(v1.w * 8388608.0f) << 9;
    }
    uint32_t* tp = thresh + (size_t)b * 800 + d0;
    *(uint4*)tp       = T0;
    *(uint4*)(tp + 4) = T1;
  }
}

// ---------------------------------------------------------------------------
// F: fused spikegen + GEMM + LIF1. grid 1024 x 256 (4 blocks/CU). Block owns
// batch rows [bid*8, bid*8+8) for ALL t. 4 groups of 5 t, double-buffered
// sM, ONE barrier per group. Wave w owns cols [32w, 32w+32) = mask word w.
// sM rows 8..15 are zeroed once (A-fragments read 16 rows; upper half = 0).
// ---------------------------------------------------------------------------
__global__ __launch_bounds__(256) void spike_lif1(
    const uint32_t* __restrict__ thresh, const ushort_t* __restrict__ wp,
    const float* __restrict__ b1, uint32_t* __restrict__ masks) {
#pragma clang fp contract(off)
  __shared__ uint32_t sM[2][5][16][25];             // 16 KB mask words
  __shared__ __align__(16) uint32_t sLUT[256][4];   // 4 KB byte -> short8 bf16

  const int tid    = threadIdx.x;
  const int bid    = blockIdx.x;
  const int b_row0 = bid << 3;        // batch rows [b_row0, b_row0+8)

  // ---- LUT init: entry tid = bf16 {0,1} expansion of byte tid ----
  {
    uint32_t v = (uint32_t)tid;
    sLUT[v][0] = ((v &   1u) ? 0x3F80u : 0u) | ((v &   2u) ? 0x3F800000u : 0u);
    sLUT[v][1] = ((v &   4u) ? 0x3F80u : 0u) | ((v &   8u) ? 0x3F800000u : 0u);
    sLUT[v][2] = ((v &  16u) ? 0x3F80u : 0u) | ((v &  32u) ? 0x3F800000u : 0u);
    sLUT[v][3] = ((v &  64u) ? 0x3F80u : 0u) | ((v & 128u) ? 0x3F800000u : 0u);
  }
  // ---- zero sM rows 8..15 (both buffers, all tt): 10 chunks x 200 dwords --
  {
    uint32_t* sMf = &sM[0][0][0][0];
    for (int i = tid; i < 2000; i += 256) {
      int c   = i / 200;              // buf*5+tt, 0..9
      int off = i - c * 200;          // 0..199 -> rows 8..15
      sMf[c * 400 + 200 + off] = 0u;
    }
  }

  const int wave = tid >> 6, lane = tid & 63;
  const int lm   = lane & 15, quad = lane >> 4;
  const int qsh  = quad << 3;

  const ushort_t* wbase = wp + (size_t)(wave * 32 + lm) * 800 + qsh;
  const float bias0 = b1[wave * 32 + lm];
  const float bias1 = b1[wave * 32 + 16 + lm];

  f32x4 mem0 = {0.f, 0.f, 0.f, 0.f};   // rows quad*4+rl, cols 32w+lm
  f32x4 mem1 = {0.f, 0.f, 0.f, 0.f};   // rows quad*4+rl, cols 32w+16+lm

  for (int g = 0; g < 4; ++g) {
    const int t0  = 5 * g;
    const int buf = g & 1;

    // ---- phase 1: spikegen, wave range [250*wave, 250*wave+250) ----
    const int base = 250 * wave;
    for (int it = 0; it < 4; ++it) {
      if (it < 3 || lane < 58) {        // 250 = 3*64 + 58
        int widx = base + it * 64 + lane;   // 0..999
        int tt  = widx / 200;           // 0..4
        int rem = widx - tt * 200;
        int r   = rem / 25;             // 0..7
        int w   = rem - r * 25;         // 0..24
        const uint32_t* tp = thresh + (size_t)(b_row0 + r) * 800 + (w << 5);
        uint32_t Ts[32];
#pragma unroll
        for (int q = 0; q < 8; ++q) {
          uint4 v = *(const uint4*)(tp + q * 4);
          Ts[q * 4 + 0] = v.x; Ts[q * 4 + 1] = v.y;
          Ts[q * 4 + 2] = v.z; Ts[q * 4 + 3] = v.w;
        }
        const uint32_t nw =
            ((uint32_t)(t0 + tt) * 8192u + (uint32_t)(b_row0 + r)) * 784u +
            ((uint32_t)w << 5);
        uint32_t word = 0u;
#pragma unroll
        for (int j = 31; j >= 0; --j) { // descending: bit j lands at pos j
          uint32_t o0, o1;
          threefry_0_42(nw + (uint32_t)j, o0, o1);
          uint32_t bits = o0 ^ o1;
          asm("v_cmp_lt_u32 vcc, %1, %2\n\t"
              "v_addc_co_u32 %0, vcc, %0, %0, vcc"
              : "+v"(word) : "v"(bits), "v"(Ts[j]) : "vcc");
        }
        sM[buf][tt][r][w] = word;
      }
    }
    __syncthreads();

    // ---- phase 2: GEMM for 5 t with shared B-fragments ----
    f32x4 acc[5][2];
#pragma unroll
    for (int tt = 0; tt < 5; ++tt) {
      acc[tt][0] = (f32x4){0.f, 0.f, 0.f, 0.f};
      acc[tt][1] = (f32x4){0.f, 0.f, 0.f, 0.f};
    }
    for (int ko = 0; ko < 25; ++ko) {
      short8 a[5];
#pragma unroll
      for (int tt = 0; tt < 5; ++tt) {
        uint32_t word = sM[buf][tt][lm][ko];
        a[tt] = *(const short8*)&sLUT[(word >> qsh) & 0xffu][0];
      }
      const int kof = ko << 5;
#pragma unroll
      for (int p = 0; p < 3; ++p) {
#pragma unroll
        for (int nn = 0; nn < 2; ++nn) {
          short8 bf = *(const short8*)&wbase[p * 102400 + nn * 12800 + kof];
#pragma unroll
          for (int tt = 0; tt < 5; ++tt)
            acc[tt][nn] = __builtin_amdgcn_mfma_f32_16x16x32_bf16(
                a[tt], bf, acc[tt][nn], 0, 0, 0);
        }
      }
    }

    // ---- LIF1 update in registers + ballot pack (t ascending) ----
#pragma unroll
    for (int tt = 0; tt < 5; ++tt) {
      const int t = t0 + tt;
      unsigned long long bk0[4], bk1[4];
#pragma unroll
      for (int rl = 0; rl < 4; ++rl) {
        float cv0 = acc[tt][0][rl] + bias0;   // == old cur1 store/load value
        float m0  = mem0[rl];
        float r0  = (m0 > 1.0f) ? 1.0f : 0.0f;
        m0 = 0.9f * m0;
        m0 = m0 + cv0;
        m0 = m0 - r0;
        mem0[rl] = m0;
        float cv1 = acc[tt][1][rl] + bias1;
        float m1  = mem1[rl];
        float r1  = (m1 > 1.0f) ? 1.0f : 0.0f;
        m1 = 0.9f * m1;
        m1 = m1 + cv1;
        m1 = m1 - r1;
        mem1[rl] = m1;
        // ballot bit(lane=16q+lm) = spike(row=4q+rl, col 32w+16nn+lm)
        bk0[rl] = __ballot(m0 > 1.0f);
        bk1[rl] = __ballot(m1 > 1.0f);
      }
      // row = lane (<8) = 4q+rl -> q=lane>>2 in {0,1}, rl=lane&3; word w:
      // bits 15..0 = k0[rl]>>(16q), bits 31..16 = k1[rl]>>(16q).
      if (lane < 8) {
        const int q  = lane >> 2;
        const int rl = lane & 3;
        unsigned long long s0 =
            (rl & 2) ? ((rl & 1) ? bk0[3] : bk0[2])
                     : ((rl & 1) ? bk0[1] : bk0[0]);
        unsigned long long s1 =
            (rl & 2) ? ((rl & 1) ? bk1[3] : bk1[2])
                     : ((rl & 1) ? bk1[1] : bk1[0]);
        uint32_t wd = ((uint32_t)(s0 >> (16 * q)) & 0xffffu) |
                      (((uint32_t)(s1 >> (16 * q)) & 0xffffu) << 16);
        masks[((size_t)t * B_SZ + b_row0 + lane) * 4 + wave] = wd;
      }
    }
  }
}

// ---------------------------------------------------------------------------
// B2: layer-2 ascending-h add chain + LIF2 (byte-identical to r9-r22).
// ---------------------------------------------------------------------------
__global__ __launch_bounds__(320) void lif2_seq(
    const float* __restrict__ w2, const float* __restrict__ b2,
    const uint32_t* __restrict__ masks, float* __restrict__ out) {
#pragma clang fp contract(off)
  __shared__ __align__(16) float sW2[O_SZ][H_SZ];
  const int tid = threadIdx.x;
  for (int i = tid; i < O_SZ * H_SZ; i += 320)
    sW2[i >> 7][i & 127] = w2[i];
  __syncthreads();

  const int wave = tid >> 6;
  const int lane = tid & 63;
  const int row  = ((blockIdx.x >> 1) << 6) + lane;
  const int o    = (blockIdx.x & 1) * 5 + wave;
  const float bias = b2[o];

  float mem2 = 0.0f;
  int cnt = 0;
  const uint4* mbase = (const uint4*)masks;

  for (int t = 0; t < T_STEPS; ++t) {
    uint4 m = mbase[(size_t)t * B_SZ + row];
    uint32_t mw[4] = {m.x, m.y, m.z, m.w};
    float acc = 0.0f;
#pragma unroll
    for (int w = 0; w < 4; ++w) {
#pragma unroll
      for (int hc = 0; hc < 8; ++hc) {
        float4 wv = *(const float4*)&sW2[o][w * 32 + hc * 4];
        float vv[4] = {wv.x, wv.y, wv.z, wv.w};
#pragma unroll
        for (int bb = 0; bb < 4; ++bb) {
          float val = ((mw[w] >> (hc * 4 + bb)) & 1u) ? vv[bb] : 0.0f;
          acc = acc + val;
        }
      }
    }
    float c2 = acc + bias;
    float reset = (mem2 > 1.0f) ? 1.0f : 0.0f;
    mem2 = 0.9f * mem2;
    mem2 = mem2 + c2;
    mem2 = mem2 - reset;
    cnt += (mem2 > 1.0f) ? 1 : 0;
  }
  out[row * O_SZ + o] = (float)cnt / 20.0f;
}

extern "C" void kernel_launch(void* const* d_in, const int* in_sizes, int n_in,
                              void* d_out, int out_size, void* d_ws, size_t ws_size,
                              hipStream_t stream) {
  const float* x   = (const float*)d_in[0];  // [8192,784]
  const float* w1  = (const float*)d_in[1];  // [128,784]
  const float* b1  = (const float*)d_in[2];  // [128]
  const float* w2  = (const float*)d_in[3];  // [10,128]
  const float* b2  = (const float*)d_in[4];  // [10]
  float* out  = (float*)d_out;               // [8192,10]
  uint32_t* masks  = (uint32_t*)((char*)d_ws + MASKS_OFF);
  ushort_t* wp     = (ushort_t*)((char*)d_ws + WP_OFF);
  uint32_t* thresh = (uint32_t*)((char*)d_ws + THR_OFF);

  prep      <<<dim3(3328), dim3(256), 0, stream>>>(w1, x, wp, thresh);
  spike_lif1<<<dim3(1024), dim3(256), 0, stream>>>(thresh, wp, b1, masks);
  lif2_seq  <<<dim3(256),  dim3(320), 0, stream>>>(w2, b2, masks, out);
}

// Round 8
// 397.605 us; speedup vs baseline: 1.1606x; 1.1606x over previous
//
#include <hip/hip_runtime.h>
#include <cstdint>

// SpikingCNN: B=8192, D=784, H=128, O=10, T=20, beta=0.9, thr=1.0
// R24 = R22 revert + lif2 FUSION. R23 post-mortem: 8-row/4-block variant
// regressed (occupancy 22.5->27% only, VALU busy TIME 288->341us: doubled
// phase-2 overhead, no idle filled) -> the ~288us VALU floor can't be bought
// with residency. R22 is the verified best (total 399.7, spike_lif1 327).
// ~50us of the remaining 73us is launch gaps (~12-15us/kernel, consistent
// R16/R22). R24 deletes one launch: each block owns its 16 batch rows for
// ALL 20 t, which is exactly lif2's data need -> keep spike words in LDS
// (sSpk[20][16][4], 5KB), run the lif2 chain in-block after the last group
// (byte-identical loop body to lif2_seq: same uint4 word values, same sW2
// staging, same w/hc/bb ascending-h order, contract off), store 160
// consecutive out floats. masks buffer + lif2 kernel deleted.
// Exactness chain (all harness-verified absmax 0.0 through R22):
//  - RNG: nw=(t*8192+b)*784+32w, bits=o0^o1 of threefry((0,42),(0,n)),
//    cmp+addc accumulate, j descending; add3 injection fusion (R19).
//  - GEMM per-element accumulation order ko->p (r12); C/D layout
//    col=lane&15, row=quad*4+reg (r10).
//  - LIF1 reset/(0.9m)/+cv/-reset, cv=acc+bias (R22).
//  - LIF2: identical op order to lif2_seq (this round: moved in-block).
// prep byte-identical.

#define T_STEPS 20
#define B_SZ   8192
#define D_SZ   784
#define H_SZ   128
#define O_SZ   10
#define WP_OFF      84541440u                 // weight planes: 614,400 B
#define THR_OFF     101539840u                // thresholds: 8192*800*4 = 26,214,400 B

typedef __attribute__((ext_vector_type(8))) short short8;
typedef __attribute__((ext_vector_type(4))) float f32x4;
typedef unsigned short ushort_t;

// rotl via v_alignbit_b32 (r15-verified: 1 instr/round).
#define ROTL_ASM(dst, src, sh)                                        \
  asm("v_alignbit_b32 %0, %1, %1, %2" : "=v"(dst) : "v"(src), "n"(32 - (sh)))

// JAX threefry2x32, key = (0, 42), counter = (0, c1). Injection adds fused
// via v_add3_u32 (associative u32 adds: bit-exact; R19-verified).
__device__ __forceinline__ void threefry_0_42(uint32_t c1,
                                              uint32_t& o0, uint32_t& o1) {
  const uint32_t ks1 = 42u;
  const uint32_t ks2 = 42u ^ 0x1BD11BDAu;
  uint32_t x0, x1, r;
  x1 = c1 + ks1;                 // x0 = c0 + ks0 = 0
  x0 = x1;                       // round 1: x0 = 0 + x1
  ROTL_ASM(r, x1, 13); x1 = r ^ x0;
#define TF_R(rot) { x0 += x1; ROTL_ASM(r, x1, rot); x1 = r ^ x0; }
#define TF_IR(C1, K0, rot) { x1 += (C1); x0 = x0 + (K0) + x1; \
                             ROTL_ASM(r, x1, rot); x1 = r ^ x0; }
  TF_R(15) TF_R(26) TF_R(6)
  TF_IR(ks2 + 1u, ks1, 17) TF_R(29) TF_R(16) TF_R(24)
  TF_IR(2u,       ks2, 13) TF_R(15) TF_R(26) TF_R(6)
  TF_IR(ks1 + 3u, 0u,  17) TF_R(29) TF_R(16) TF_R(24)
  TF_IR(ks2 + 4u, ks1, 13) TF_R(15) TF_R(26) TF_R(6)
#undef TF_R
#undef TF_IR
  x0 += ks2; x1 += 5u;           // final injection (ks0+5 = 5)
  o0 = x0; o1 = x1;
}

__device__ __forceinline__ uint32_t rne_bf16_bits(float f) {
  uint32_t u = __float_as_uint(f);
  return (u + 0x7fffu + ((u >> 16) & 1u)) & 0xffff0000u;
}

// ---------------------------------------------------------------------------
// P: prep. Blocks 0..127: split w1 into 3 exact bf16 planes [128][800].
// Blocks 128..3327: pre-shifted thresholds thresh[b][d] = ceil(x*2^23)<<9,
// d in [784,800) padded 0 (never spikes; hits only zero weights).
// ---------------------------------------------------------------------------
__global__ __launch_bounds__(256) void prep(
    const float* __restrict__ w1, const float* __restrict__ x,
    ushort_t* __restrict__ wp, uint32_t* __restrict__ thresh) {
  if (blockIdx.x < 128) {
    const int h = blockIdx.x;
    for (int k = threadIdx.x; k < 800; k += 256) {
      float w = (k < D_SZ) ? w1[h * D_SZ + k] : 0.0f;
      uint32_t hb = rne_bf16_bits(w);
      float hi = __uint_as_float(hb);
      float r1 = w - hi;                      // exact
      uint32_t mb = rne_bf16_bits(r1);
      float mid = __uint_as_float(mb);
      float lo = r1 - mid;                    // exact
      uint32_t lb = __float_as_uint(lo);
      wp[0 * 102400 + h * 800 + k] = (ushort_t)(hb >> 16);
      wp[1 * 102400 + h * 800 + k] = (ushort_t)(mb >> 16);
      wp[2 * 102400 + h * 800 + k] = (ushort_t)(lb >> 16);
    }
  } else {
    const int gid = (blockIdx.x - 128) * 256 + threadIdx.x;  // 0..819199
    const int b = gid / 100;
    const int y = gid - b * 100;
    const int d0 = y << 3;
    uint4 T0 = {0u, 0u, 0u, 0u}, T1 = {0u, 0u, 0u, 0u};
    if (y < 98) {                                  // d0+7 <= 783
      const float* xr = x + (size_t)b * D_SZ + d0;
      float4 v0 = *(const float4*)xr;
      float4 v1 = *(const float4*)(xr + 4);
      T0.x = (uint32_t)__builtin_ceilf(v0.x * 8388608.0f) << 9;
      T0.y = (uint32_t)__builtin_ceilf(v0.y * 8388608.0f) << 9;
      T0.z = (uint32_t)__builtin_ceilf(v0.z * 8388608.0f) << 9;
      T0.w = (uint32_t)__builtin_ceilf(v0.w * 8388608.0f) << 9;
      T1.x = (uint32_t)__builtin_ceilf(v1.x * 8388608.0f) << 9;
      T1.y = (uint32_t)__builtin_ceilf(v1.y * 8388608.0f) << 9;
      T1.z = (uint32_t)__builtin_ceilf(v1.z * 8388608.0f) << 9;
      T1.w = (uint32_t)__builtin_ceilf(v1.w * 8388608.0f) << 9;
    }
    uint32_t* tp = thresh + (size_t)b * 800 + d0;
    *(uint4*)tp       = T0;
    *(uint4*)(tp + 4) = T1;
  }
}

// ---------------------------------------------------------------------------
// F: fused spikegen + GEMM + LIF1 + LIF2. grid 512 x 256 (2 blocks/CU).
// Block owns batch rows [bid*16, bid*16+16) for ALL t. 4 groups of 5 t,
// double-buffered sM, ONE barrier per group. Wave w owns cols [32w,32w+32)
// = spike word w. Spike words kept in LDS (sSpk); epilogue runs the exact
// lif2_seq chain for the block's 16 rows and writes out directly.
// ---------------------------------------------------------------------------
__global__ __launch_bounds__(256) void spike_lif1(
    const uint32_t* __restrict__ thresh, const ushort_t* __restrict__ wp,
    const float* __restrict__ b1, const float* __restrict__ w2,
    const float* __restrict__ b2, float* __restrict__ out) {
#pragma clang fp contract(off)
  __shared__ uint32_t sM[2][5][16][25];             // 16 KB mask words
  __shared__ __align__(16) uint32_t sLUT[256][4];   // 4 KB byte -> short8 bf16
  __shared__ __align__(16) uint32_t sSpk[T_STEPS][16][4];  // 5 KB spike words
  __shared__ __align__(16) float sW2[O_SZ][H_SZ];   // 5 KB

  const int tid    = threadIdx.x;
  const int bid    = blockIdx.x;
  const int b_row0 = bid << 4;        // batch rows [b_row0, b_row0+16)

  // ---- LUT init + w2 staging (read in epilogue / after barriers) ----
  {
    uint32_t v = (uint32_t)tid;
    sLUT[v][0] = ((v &   1u) ? 0x3F80u : 0u) | ((v &   2u) ? 0x3F800000u : 0u);
    sLUT[v][1] = ((v &   4u) ? 0x3F80u : 0u) | ((v &   8u) ? 0x3F800000u : 0u);
    sLUT[v][2] = ((v &  16u) ? 0x3F80u : 0u) | ((v &  32u) ? 0x3F800000u : 0u);
    sLUT[v][3] = ((v &  64u) ? 0x3F80u : 0u) | ((v & 128u) ? 0x3F800000u : 0u);
    for (int i = tid; i < O_SZ * H_SZ; i += 256)
      sW2[i >> 7][i & 127] = w2[i];
  }

  const int wave = tid >> 6, lane = tid & 63;
  const int lm   = lane & 15, quad = lane >> 4;
  const int qsh  = quad << 3;

  const ushort_t* wbase = wp + (size_t)(wave * 32 + lm) * 800 + qsh;
  const float bias0 = b1[wave * 32 + lm];
  const float bias1 = b1[wave * 32 + 16 + lm];

  f32x4 mem0 = {0.f, 0.f, 0.f, 0.f};   // rows quad*4+rl, cols 32w+lm
  f32x4 mem1 = {0.f, 0.f, 0.f, 0.f};   // rows quad*4+rl, cols 32w+16+lm

  for (int g = 0; g < 4; ++g) {
    const int t0  = 5 * g;
    const int buf = g & 1;

    // ---- phase 1: spikegen, wave range [500*wave, 500*wave+500) ----
    const int base = 500 * wave;
    for (int it = 0; it < 8; ++it) {
      if (it < 7 || lane < 52) {        // 500 = 7*64 + 52
        int widx = base + it * 64 + lane;
        int tt  = widx / 400;           // 0..4
        int rem = widx - tt * 400;
        int r   = rem / 25;             // 0..15
        int w   = rem - r * 25;         // 0..24
        const uint32_t* tp = thresh + (size_t)(b_row0 + r) * 800 + (w << 5);
        uint32_t Ts[32];
#pragma unroll
        for (int q = 0; q < 8; ++q) {
          uint4 v = *(const uint4*)(tp + q * 4);
          Ts[q * 4 + 0] = v.x; Ts[q * 4 + 1] = v.y;
          Ts[q * 4 + 2] = v.z; Ts[q * 4 + 3] = v.w;
        }
        const uint32_t nw =
            ((uint32_t)(t0 + tt) * 8192u + (uint32_t)(b_row0 + r)) * 784u +
            ((uint32_t)w << 5);
        uint32_t word = 0u;
#pragma unroll
        for (int j = 31; j >= 0; --j) { // descending: bit j lands at pos j
          uint32_t o0, o1;
          threefry_0_42(nw + (uint32_t)j, o0, o1);
          uint32_t bits = o0 ^ o1;
          asm("v_cmp_lt_u32 vcc, %1, %2\n\t"
              "v_addc_co_u32 %0, vcc, %0, %0, vcc"
              : "+v"(word) : "v"(bits), "v"(Ts[j]) : "vcc");
        }
        sM[buf][tt][r][w] = word;
      }
    }
    __syncthreads();

    // ---- phase 2: GEMM for 5 t with shared B-fragments ----
    f32x4 acc[5][2];
#pragma unroll
    for (int tt = 0; tt < 5; ++tt) {
      acc[tt][0] = (f32x4){0.f, 0.f, 0.f, 0.f};
      acc[tt][1] = (f32x4){0.f, 0.f, 0.f, 0.f};
    }
    for (int ko = 0; ko < 25; ++ko) {
      short8 a[5];
#pragma unroll
      for (int tt = 0; tt < 5; ++tt) {
        uint32_t word = sM[buf][tt][lm][ko];
        a[tt] = *(const short8*)&sLUT[(word >> qsh) & 0xffu][0];
      }
      const int kof = ko << 5;
#pragma unroll
      for (int p = 0; p < 3; ++p) {
#pragma unroll
        for (int nn = 0; nn < 2; ++nn) {
          short8 bf = *(const short8*)&wbase[p * 102400 + nn * 12800 + kof];
#pragma unroll
          for (int tt = 0; tt < 5; ++tt)
            acc[tt][nn] = __builtin_amdgcn_mfma_f32_16x16x32_bf16(
                a[tt], bf, acc[tt][nn], 0, 0, 0);
        }
      }
    }

    // ---- LIF1 update in registers + ballot pack -> sSpk (t ascending) ----
#pragma unroll
    for (int tt = 0; tt < 5; ++tt) {
      const int t = t0 + tt;
      unsigned long long bk0[4], bk1[4];
#pragma unroll
      for (int rl = 0; rl < 4; ++rl) {
        float cv0 = acc[tt][0][rl] + bias0;   // == old cur1 store/load value
        float m0  = mem0[rl];
        float r0  = (m0 > 1.0f) ? 1.0f : 0.0f;
        m0 = 0.9f * m0;
        m0 = m0 + cv0;
        m0 = m0 - r0;
        mem0[rl] = m0;
        float cv1 = acc[tt][1][rl] + bias1;
        float m1  = mem1[rl];
        float r1  = (m1 > 1.0f) ? 1.0f : 0.0f;
        m1 = 0.9f * m1;
        m1 = m1 + cv1;
        m1 = m1 - r1;
        mem1[rl] = m1;
        // ballot bit(lane=16q+lm) = spike(row=4q+rl, col 32w+16nn+lm)
        bk0[rl] = __ballot(m0 > 1.0f);
        bk1[rl] = __ballot(m1 > 1.0f);
      }
      // row = lane (<16) = 4q+rl -> q=lane>>2, rl=lane&3; word w of that row:
      // bits 15..0 = k0[rl]>>(16q), bits 31..16 = k1[rl]>>(16q).
      if (lane < 16) {
        const int q  = lane >> 2;
        const int rl = lane & 3;
        unsigned long long s0 =
            (rl & 2) ? ((rl & 1) ? bk0[3] : bk0[2])
                     : ((rl & 1) ? bk0[1] : bk0[0]);
        unsigned long long s1 =
            (rl & 2) ? ((rl & 1) ? bk1[3] : bk1[2])
                     : ((rl & 1) ? bk1[1] : bk1[0]);
        uint32_t wd = ((uint32_t)(s0 >> (16 * q)) & 0xffffu) |
                      (((uint32_t)(s1 >> (16 * q)) & 0xffffu) << 16);
        sSpk[t][lane][wave] = wd;
      }
    }
  }
  __syncthreads();

  // ---- epilogue: LIF2 for this block's 16 rows (lif2_seq chain, exact) ----
  if (tid < 160) {
    const int row = tid / 10;          // 0..15 (out store: consecutive tid ->
    const int o   = tid - row * 10;    //        consecutive out index)
    const float bias = b2[o];
    float mem2 = 0.0f;
    int cnt = 0;
    for (int t = 0; t < T_STEPS; ++t) {
      uint4 m = *(const uint4*)&sSpk[t][row][0];
      uint32_t mw[4] = {m.x, m.y, m.z, m.w};
      float acc = 0.0f;
#pragma unroll
      for (int w = 0; w < 4; ++w) {
#pragma unroll
        for (int hc = 0; hc < 8; ++hc) {
          float4 wv = *(const float4*)&sW2[o][w * 32 + hc * 4];
          float vv[4] = {wv.x, wv.y, wv.z, wv.w};
#pragma unroll
          for (int bb = 0; bb < 4; ++bb) {
            float val = ((mw[w] >> (hc * 4 + bb)) & 1u) ? vv[bb] : 0.0f;
            acc = acc + val;
          }
        }
      }
      float c2 = acc + bias;
      float reset = (mem2 > 1.0f) ? 1.0f : 0.0f;
      mem2 = 0.9f * mem2;
      mem2 = mem2 + c2;
      mem2 = mem2 - reset;
      cnt += (mem2 > 1.0f) ? 1 : 0;
    }
    out[(size_t)b_row0 * O_SZ + tid] = (float)cnt / 20.0f;
  }
}

extern "C" void kernel_launch(void* const* d_in, const int* in_sizes, int n_in,
                              void* d_out, int out_size, void* d_ws, size_t ws_size,
                              hipStream_t stream) {
  const float* x   = (const float*)d_in[0];  // [8192,784]
  const float* w1  = (const float*)d_in[1];  // [128,784]
  const float* b1  = (const float*)d_in[2];  // [128]
  const float* w2  = (const float*)d_in[3];  // [10,128]
  const float* b2  = (const float*)d_in[4];  // [10]
  float* out  = (float*)d_out;               // [8192,10]
  ushort_t* wp     = (ushort_t*)((char*)d_ws + WP_OFF);
  uint32_t* thresh = (uint32_t*)((char*)d_ws + THR_OFF);

  prep      <<<dim3(3328), dim3(256), 0, stream>>>(w1, x, wp, thresh);
  spike_lif1<<<dim3(512),  dim3(256), 0, stream>>>(thresh, wp, b1, w2, b2, out);
}